// Round 4
// baseline (471.356 us; speedup 1.0000x reference)
//
#include <hip/hip_runtime.h>
#include <hip/hip_bf16.h>
#include <math.h>

// Problem dims
constexpr int BD = 32;
constexpr int SD = 512;
constexpr int RD = 49;
constexpr int HD = 768;
constexpr int MT = BD * SD;    // 16384 text rows
constexpr int MI = BD * RD;    // 1568 img rows
constexpr int NP = 12;         // 6 n-blocks x 2 wave-columns partials per row
constexpr int MBT = MT / 128;  // 128 text m-blocks
constexpr int MBI = 13;        // img m-blocks (1664 padded rows; OOB-safe, see launcher)
constexpr int NWG = (MBT + MBI) * 6;  // 846 gemm blocks
constexpr int NT2 = HD / 64;   // 12 K-steps (BK=64)

typedef __bf16 bf16;
typedef __bf16 bf16x4 __attribute__((ext_vector_type(4)));
typedef __bf16 bf16x8 __attribute__((ext_vector_type(8)));
typedef float f32x4 __attribute__((ext_vector_type(4)));

#define GLOAD_LDS16(g, l) __builtin_amdgcn_global_load_lds( \
    (__attribute__((address_space(1))) void*)(g),           \
    (__attribute__((address_space(3))) void*)(l), 16, 0, 0)

__device__ __forceinline__ float fast_tanh(float x) {
    const float e = __expf(2.f * x);
    return 1.f - 2.f / (e + 1.f);
}

// ---------------------------------------------------------------------------
// prep_text: text fp32 -> text_bf (bf16) AND s_txt[row] = text[row,:].v_f
// ---------------------------------------------------------------------------
__global__ __launch_bounds__(256) void prep_text(
    const float* __restrict__ text, const float* __restrict__ v_f,
    bf16* __restrict__ text_bf, float* __restrict__ s_txt)
{
    const int row = blockIdx.x * 4 + (threadIdx.x >> 6);
    const int lane = threadIdx.x & 63;
    const float* tr = text + (size_t)row * HD;
    bf16* tb = text_bf + (size_t)row * HD;
    float acc = 0.f;
    #pragma unroll
    for (int c = 0; c < 3; ++c) {
        const int o = c * 256 + lane * 4;
        const f32x4 x = *(const f32x4*)(tr + o);
        const f32x4 v = *(const f32x4*)(v_f + o);
        bf16x4 b; b[0] = (bf16)x[0]; b[1] = (bf16)x[1]; b[2] = (bf16)x[2]; b[3] = (bf16)x[3];
        *(bf16x4*)(tb + o) = b;
        acc += x[0] * v[0] + x[1] * v[1] + x[2] * v[2] + x[3] * v[3];
    }
    for (int off = 32; off; off >>= 1) acc += __shfl_xor(acc, off);
    if (lane == 0) s_txt[row] = acc;
}

// ---------------------------------------------------------------------------
// prep_misc: fused vf_vm (385 blk) + conv_img (588 blk) + transpose_w (288 blk)
// ---------------------------------------------------------------------------
__global__ __launch_bounds__(256) void prep_misc(
    const float* __restrict__ ft_w, const float* __restrict__ fm_w,
    const float* __restrict__ fm_b, const float* __restrict__ fg_w,
    float* __restrict__ v_f, float* __restrict__ v_m, float* __restrict__ c_m,
    const float* __restrict__ img, bf16* __restrict__ img_bf,
    const float* __restrict__ t2_w, const float* __restrict__ i1_w,
    bf16* __restrict__ wt_t, bf16* __restrict__ wt_i)
{
    __shared__ float tile[64][65];
    const int bid = blockIdx.x;
    if (bid < 385) {
        const int idx = bid * 4 + (threadIdx.x >> 6);
        const int lane = threadIdx.x & 63;
        const float* row; const float* vecp; float* outp;
        if (idx < HD)            { row = ft_w + (size_t)idx * HD;        vecp = fg_w;      outp = v_f + idx; }
        else if (idx < 2 * HD)   { row = fm_w + (size_t)(idx - HD) * HD; vecp = fg_w + HD; outp = v_m + (idx - HD); }
        else if (idx == 2 * HD)  { row = fm_b;                           vecp = fg_w + HD; outp = c_m; }
        else return;
        float acc = 0.f;
        #pragma unroll
        for (int i = 0; i < HD / 64; ++i) acc += row[lane + 64 * i] * vecp[lane + 64 * i];
        for (int off = 32; off; off >>= 1) acc += __shfl_xor(acc, off);
        if (lane == 0) *outp = acc;
    } else if (bid < 385 + 588) {
        const int i = (bid - 385) * 256 + threadIdx.x;
        const int n8 = BD * RD * HD / 8;
        if (i >= n8) return;
        const size_t o = (size_t)i * 8;
        const f32x4 x0 = *(const f32x4*)(img + o);
        const f32x4 x1 = *(const f32x4*)(img + o + 4);
        bf16x8 b;
        b[0]=(bf16)x0[0]; b[1]=(bf16)x0[1]; b[2]=(bf16)x0[2]; b[3]=(bf16)x0[3];
        b[4]=(bf16)x1[0]; b[5]=(bf16)x1[1]; b[6]=(bf16)x1[2]; b[7]=(bf16)x1[3];
        *(bf16x8*)(img_bf + o) = b;
    } else {
        const int idx2 = bid - (385 + 588);
        const int z = idx2 / 144, rem = idx2 % 144;
        const int bx = rem % 12, by = rem / 12;
        const float* W = z ? i1_w : t2_w;
        bf16* Wt = z ? wt_i : wt_t;
        const int k0 = bx * 64, n0 = by * 64;
        const int t = threadIdx.x;
        const int rb = t >> 6, c = t & 63;
        #pragma unroll
        for (int i = 0; i < 16; ++i) {
            const int r = rb + i * 4;
            tile[r][c] = W[(size_t)(k0 + r) * HD + n0 + c];
        }
        __syncthreads();
        #pragma unroll
        for (int i = 0; i < 16; ++i) {
            const int r = rb + i * 4;
            Wt[(size_t)(n0 + r) * HD + k0 + c] = (bf16)tile[c][r];
        }
    }
}

// ---------------------------------------------------------------------------
// gemm2: merged score GEMMs. 128x128 tile, BK=64, single-buffered LDS (32KB),
// conflict-free chunked LDS layout, XCD-bijective swizzle. (unchanged R3)
// ---------------------------------------------------------------------------
__global__ __launch_bounds__(256, 4) void gemm2(
    const bf16* __restrict__ Atext, const bf16* __restrict__ WtT,
    const float* __restrict__ vecT, float* __restrict__ partT,
    const bf16* __restrict__ Aimg, const bf16* __restrict__ WtI,
    const float* __restrict__ vecI, float* __restrict__ partI)
{
    __shared__ __align__(16) bf16 As[16 * 512];
    __shared__ __align__(16) bf16 Bs[16 * 512];

    const int bid = blockIdx.x;
    const int q = NWG / 8, r = NWG % 8;
    const int xcd = bid % 8, sidx = bid / 8;
    const int o = (xcd < r ? xcd * (q + 1) : r * (q + 1) + (xcd - r) * q) + sidx;
    const int mb = o / 6, nb = o % 6;

    const bool isT = mb < MBT;
    const bf16* A    = isT ? Atext : Aimg;
    const bf16* Wt   = isT ? WtT : WtI;
    const float* vec = isT ? vecT : vecI;
    float* part      = isT ? partT : partI;
    const int m0 = (isT ? mb : mb - MBT) * 128;
    const int n0 = nb * 128;

    const int t = threadIdx.x;
    const int w = t >> 6, lane = t & 63;
    const int quad = lane >> 4, l16 = lane & 15;
    const int wm2 = (w >> 1) * 64, wn2 = (w & 1) * 64;

    const bf16* Ag = A  + (size_t)(m0 + l16) * HD + quad * 8;
    const bf16* Bg = Wt + (size_t)(n0 + l16) * HD + quad * 8;

    f32x4 acc[4][4] = {};

    for (int tt = 0; tt < NT2; ++tt) {
        const int kk = tt * 64;
        #pragma unroll
        for (int h = 0; h < 2; ++h) {
            #pragma unroll
            for (int j = 0; j < 2; ++j) {
                const int rc = 2 * w + j;
                GLOAD_LDS16(Ag + (size_t)rc * 16 * HD + kk + h * 32, As + (h * 8 + rc) * 512);
                GLOAD_LDS16(Bg + (size_t)rc * 16 * HD + kk + h * 32, Bs + (h * 8 + rc) * 512);
            }
        }
        __syncthreads();

        #pragma unroll
        for (int h = 0; h < 2; ++h) {
            bf16x8 af[4], bg4[4];
            #pragma unroll
            for (int f = 0; f < 4; ++f) {
                af[f]  = *(const bf16x8*)(As + (h * 8 + wm2 / 16 + f) * 512 + lane * 8);
                bg4[f] = *(const bf16x8*)(Bs + (h * 8 + wn2 / 16 + f) * 512 + lane * 8);
            }
            #pragma unroll
            for (int fi = 0; fi < 4; ++fi)
                #pragma unroll
                for (int fj = 0; fj < 4; ++fj)
                    acc[fi][fj] = __builtin_amdgcn_mfma_f32_16x16x32_bf16(af[fi], bg4[fj], acc[fi][fj], 0, 0, 0);
        }
        __syncthreads();
    }

    float vv[4];
    #pragma unroll
    for (int fj = 0; fj < 4; ++fj) vv[fj] = vec[n0 + wn2 + fj * 16 + l16];

    #pragma unroll
    for (int fi = 0; fi < 4; ++fi) {
        #pragma unroll
        for (int reg = 0; reg < 4; ++reg) {
            float p = 0.f;
            #pragma unroll
            for (int fj = 0; fj < 4; ++fj)
                p += fast_tanh(acc[fi][fj][reg]) * vv[fj];
            p += __shfl_xor(p, 1);
            p += __shfl_xor(p, 2);
            p += __shfl_xor(p, 4);
            p += __shfl_xor(p, 8);
            if (l16 == 0) {
                const int row = m0 + wm2 + fi * 16 + quad * 4 + reg;
                part[(size_t)row * NP + nb * 2 + (w & 1)] = p;
            }
        }
    }
}

// ---------------------------------------------------------------------------
// wsum2: fused partial-reduce + softmax + weighted sum.
// blocks [0,96): text (b, hy): recompute softmax of batch b from k_part in
//   LDS, then atxt[b, hy-slice] = sum_j P[j] * text_bf[b,j,h]
// blocks [96,192): img (b, hy): same from i_part over img fp32 (J=49)
// ---------------------------------------------------------------------------
__global__ __launch_bounds__(256) void wsum2(
    const float* __restrict__ k_part, const float* __restrict__ i_part,
    const bf16* __restrict__ text_bf, const float* __restrict__ img,
    float* __restrict__ atxt, float* __restrict__ aimg)
{
    __shared__ float S[SD];
    __shared__ float red[4];
    const int bid = blockIdx.x;
    const bool isText = bid < 96;
    const int idx = isText ? bid : bid - 96;
    const int b = idx & 31, hy = idx >> 5;
    const int t = threadIdx.x;

    if (isText) {
        for (int j = t; j < SD; j += 256) {
            const float* p = k_part + (size_t)(b * SD + j) * NP;
            float s = 0.f;
            #pragma unroll
            for (int u = 0; u < 3; ++u) {
                const f32x4 a = *(const f32x4*)(p + u * 4);
                s += a[0] + a[1] + a[2] + a[3];
            }
            S[j] = s;
        }
        __syncthreads();
        float m = fmaxf(S[t], S[t + 256]);
        for (int off = 32; off; off >>= 1) m = fmaxf(m, __shfl_xor(m, off));
        if ((t & 63) == 0) red[t >> 6] = m;
        __syncthreads();
        m = fmaxf(fmaxf(red[0], red[1]), fmaxf(red[2], red[3]));
        float lsum = 0.f;
        {
            const float e0 = __expf(S[t] - m), e1 = __expf(S[t + 256] - m);
            S[t] = e0; S[t + 256] = e1;
            lsum = e0 + e1;
        }
        for (int off = 32; off; off >>= 1) lsum += __shfl_xor(lsum, off);
        __syncthreads();
        if ((t & 63) == 0) red[t >> 6] = lsum;
        __syncthreads();
        const float inv = 1.f / (red[0] + red[1] + red[2] + red[3]);
        const int h = hy * 256 + t;
        const bf16* Xb = text_bf + (size_t)b * SD * HD + h;
        float acc = 0.f;
        #pragma unroll 8
        for (int j = 0; j < SD; ++j) acc += S[j] * (float)Xb[(size_t)j * HD];
        atxt[b * HD + h] = acc * inv;
    } else {
        if (t < 64) {
            float s0 = -1e30f;
            if (t < RD) {
                const float* p = i_part + (size_t)(b * RD + t) * NP;
                float s = 0.f;
                #pragma unroll
                for (int u = 0; u < 3; ++u) {
                    const f32x4 a = *(const f32x4*)(p + u * 4);
                    s += a[0] + a[1] + a[2] + a[3];
                }
                s0 = s;
            }
            float m = s0;
            for (int off = 32; off; off >>= 1) m = fmaxf(m, __shfl_xor(m, off));
            float e = (t < RD) ? __expf(s0 - m) : 0.f;
            float lsum = e;
            for (int off = 32; off; off >>= 1) lsum += __shfl_xor(lsum, off);
            if (t < RD) S[t] = e;
            if (t == 0) red[0] = 1.f / lsum;
        }
        __syncthreads();
        const float inv = red[0];
        const int h = hy * 256 + t;
        const float* Xb = img + (size_t)b * RD * HD + h;
        float acc = 0.f;
        #pragma unroll 7
        for (int j = 0; j < RD; ++j) acc += S[j] * Xb[(size_t)j * HD];
        aimg[b * HD + h] = acc * inv;
    }
}

// ---------------------------------------------------------------------------
// ni_nt2: weights-stationary batched GEMV. grid (12, 2), 512 threads.
// Wave wv owns batches [4wv, 4wv+4); lane c owns col n = bx*64+c.
// Y[b, n] = tanh(sum_k X[b,k] * W[k,n] + bias[n])
// ---------------------------------------------------------------------------
__global__ __launch_bounds__(512) void ni_nt2(
    const float* __restrict__ aimg, const float* __restrict__ atxt,
    const float* __restrict__ gi_w, const float* __restrict__ gi_b,
    const float* __restrict__ gt_w, const float* __restrict__ gt_b,
    float* __restrict__ ni, float* __restrict__ nt)
{
    const int which = blockIdx.y;
    const float* X = which ? atxt : aimg;
    const float* W = which ? gt_w : gi_w;
    const float* bias = which ? gt_b : gi_b;
    float* Y = which ? nt : ni;

    const int t = threadIdx.x;
    const int c = t & 63;
    const int wv = __builtin_amdgcn_readfirstlane(t >> 6);   // 0..7
    const int n = blockIdx.x * 64 + c;
    const float* Xb = X + (size_t)(4 * wv) * HD;

    float a0 = 0.f, a1 = 0.f, a2 = 0.f, a3 = 0.f;
    #pragma unroll 4
    for (int k = 0; k < HD; ++k) {
        const float w0 = W[(size_t)k * HD + n];
        a0 += Xb[k] * w0;
        a1 += Xb[HD + k] * w0;
        a2 += Xb[2 * HD + k] * w0;
        a3 += Xb[3 * HD + k] * w0;
    }
    const float bb = bias[n];
    Y[(size_t)(4 * wv + 0) * HD + n] = tanhf(a0 + bb);
    Y[(size_t)(4 * wv + 1) * HD + n] = tanhf(a1 + bb);
    Y[(size_t)(4 * wv + 2) * HD + n] = tanhf(a2 + bb);
    Y[(size_t)(4 * wv + 3) * HD + n] = tanhf(a3 + bb);
}

// ---------------------------------------------------------------------------
// gateT2: fused gate + mm + T GEMV, weights-stationary. grid (12), 512 thr.
// Phase1: per-batch gate + s_mm dots (16 lanes per batch).
// Phase2: Mm[k][b] (padded [768][36]) in LDS.
// Phase3: T[b, n-slice] = tanh(sum_k Mm[k][b] * fr_w[k,n] + fr_b[n])
// ---------------------------------------------------------------------------
__global__ __launch_bounds__(512) void gateT2(
    const float* __restrict__ ni, const float* __restrict__ nt,
    const float* __restrict__ gg_w, const float* __restrict__ gg_b,
    const float* __restrict__ v_m, const float* __restrict__ c_m,
    const float* __restrict__ fg_b,
    const float* __restrict__ fr_w, const float* __restrict__ fr_b,
    float* __restrict__ T, float* __restrict__ s_mm)
{
    __shared__ float Mm[HD][36];
    __shared__ float g_sh[BD];
    __shared__ float sm_sh[BD];
    const int t = threadIdx.x;

    // phase 1: gates + s_mm dot pairs
    {
        const int b = t >> 4, l = t & 15;
        const float* nib = ni + (size_t)b * HD;
        const float* ntb = nt + (size_t)b * HD;
        float dgi = 0.f, dgt = 0.f, dvi = 0.f, dvt = 0.f;
        for (int j = l; j < HD; j += 16) {
            const float a = nib[j], d = ntb[j];
            dgi += a * gg_w[j];
            dgt += d * gg_w[HD + j];
            dvi += a * v_m[j];
            dvt += d * v_m[j];
        }
        #pragma unroll
        for (int off = 8; off; off >>= 1) {
            dgi += __shfl_xor(dgi, off);
            dgt += __shfl_xor(dgt, off);
            dvi += __shfl_xor(dvi, off);
            dvt += __shfl_xor(dvt, off);
        }
        if (l == 0) {
            const float g = 1.f / (1.f + expf(-(dgi + dgt + gg_b[0])));
            g_sh[b] = g;
            sm_sh[b] = g * dvi + (1.f - g) * dvt;
        }
    }
    __syncthreads();
    if (blockIdx.x == 0 && t < BD) s_mm[t] = sm_sh[t] + c_m[0] + fg_b[0];

    // phase 2: Mm transpose-store
    for (int b = 0; b < BD; ++b) {
        const float g = g_sh[b];
        const float* nib = ni + (size_t)b * HD;
        const float* ntb = nt + (size_t)b * HD;
        for (int h = t; h < HD; h += 512)
            Mm[h][b] = g * nib[h] + (1.f - g) * ntb[h];
    }
    __syncthreads();

    // phase 3: T GEMV (fr_w slice read once per block)
    const int c = t & 63;
    const int wv = __builtin_amdgcn_readfirstlane(t >> 6);
    const int n = blockIdx.x * 64 + c;
    f32x4 acc = {0.f, 0.f, 0.f, 0.f};
    #pragma unroll 4
    for (int k = 0; k < HD; ++k) {
        const float w0 = fr_w[(size_t)k * HD + n];
        const f32x4 mv = *(const f32x4*)&Mm[k][4 * wv];
        acc[0] += mv[0] * w0;
        acc[1] += mv[1] * w0;
        acc[2] += mv[2] * w0;
        acc[3] += mv[3] * w0;
    }
    const float bb = fr_b[n];
    #pragma unroll
    for (int j = 0; j < 4; ++j)
        T[(size_t)(4 * wv + j) * HD + n] = tanhf(acc[j] + bb);
}

// out[b,s,h] = sigmoid(s_txt[b,s] + s_mm[b]) * T[b,h]  (reads ws only)
__global__ __launch_bounds__(256) void out_kernel(const float* __restrict__ s_txt,
                                                  const float* __restrict__ s_mm,
                                                  const float* __restrict__ T,
                                                  float* __restrict__ out) {
    const size_t idx = ((size_t)blockIdx.x * 256 + threadIdx.x) * 4;
    const int h = (int)(idx % HD);
    const int bs = (int)(idx / HD);
    const int b = bs >> 9;
    float f = s_txt[bs] + s_mm[b];
    f = 1.f / (1.f + expf(-f));
    const float* Tp = T + b * HD + h;
    f32x4 o;
    o[0] = f * Tp[0]; o[1] = f * Tp[1]; o[2] = f * Tp[2]; o[3] = f * Tp[3];
    *(f32x4*)(out + idx) = o;
}

// ---------------------------------------------------------------------------
extern "C" void kernel_launch(void* const* d_in, const int* in_sizes, int n_in,
                              void* d_out, int out_size, void* d_ws, size_t ws_size,
                              hipStream_t stream) {
    const float* text = (const float*)d_in[0];
    const float* img  = (const float*)d_in[1];
    const float* i1_w = (const float*)d_in[4];
    const float* a1_w = (const float*)d_in[5];
    const float* t2_w = (const float*)d_in[7];
    const float* a2_w = (const float*)d_in[10];
    const float* gt_w = (const float*)d_in[12];
    const float* gt_b = (const float*)d_in[13];
    const float* gi_w = (const float*)d_in[14];
    const float* gi_b = (const float*)d_in[15];
    const float* gg_w = (const float*)d_in[16];
    const float* gg_b = (const float*)d_in[17];
    const float* ft_w = (const float*)d_in[18];
    const float* fm_w = (const float*)d_in[19];
    const float* fm_b = (const float*)d_in[20];
    const float* fg_w = (const float*)d_in[21];
    const float* fg_b = (const float*)d_in[22];
    const float* fr_w = (const float*)d_in[23];
    const float* fr_b = (const float*)d_in[24];
    float* out = (float*)d_out;

    // ---- scratch inside d_out (all uses precede out_kernel) ----
    float* sc_ = out;
    float* i_part  = sc_;                 // 1664*12 = 19968 (cap 38400)
    float* k_part  = sc_ + 38400;         // 16384*12 = 196608
    float* aimg    = sc_ + 449600;        // 24576
    float* atxt    = sc_ + 474176;        // 24576
    float* v_f     = sc_ + 498752;        // 768
    float* v_m     = sc_ + 499520;        // 768
    float* c_m     = sc_ + 500288;        // 1 (+pad)
    float* ni      = sc_ + 598656;        // 24576
    float* nt      = sc_ + 623232;        // 24576
    bf16* text_bf  = (bf16*)(sc_ + 672384);    // 12.58M bf16
    bf16* img_bf   = (bf16*)(sc_ + 6963840);   // 1204224 bf16
    bf16* wt_t     = (bf16*)(sc_ + 7565952);   // 589824 bf16 (absorbs img OOB reads)
    bf16* wt_i     = (bf16*)(sc_ + 7860864);   // 589824 bf16 (ends 8155776 < 12.58M)

    // ---- ws holds only what out_kernel reads ----
    float* ws    = (float*)d_ws;
    float* s_txt = ws;                    // 16384
    float* s_mm  = ws + 16384;            // 32 (+pad)
    float* T     = ws + 16448;            // 24576

    // 0. fused prep: rank-1 collapses + img->bf16 + weight transposes
    prep_misc<<<dim3(385 + 588 + 288), dim3(256), 0, stream>>>(
        ft_w, fm_w, fm_b, fg_w, v_f, v_m, c_m, img, img_bf, t2_w, i1_w, wt_t, wt_i);
    // 0b. text fp32 -> bf16 + s_txt (needs v_f)
    prep_text<<<dim3(MT / 4), dim3(256), 0, stream>>>(text, v_f, text_bf, s_txt);
    // 1/2. merged score GEMMs
    gemm2<<<dim3(NWG), dim3(256), 0, stream>>>(
        text_bf, wt_t, a2_w + HD, k_part, img_bf, wt_i, a1_w + HD, i_part);
    // 3. fused reduce + softmax + weighted sums -> atxt, aimg
    wsum2<<<dim3(192), dim3(256), 0, stream>>>(
        k_part, i_part, text_bf, img, atxt, aimg);
    // 4. GMF GEMVs, weights-stationary
    ni_nt2<<<dim3(12, 2), dim3(512), 0, stream>>>(
        aimg, atxt, gi_w, gi_b, gt_w, gt_b, ni, nt);
    gateT2<<<dim3(12), dim3(512), 0, stream>>>(
        ni, nt, gg_w, gg_b, v_m, c_m, fg_b, fr_w, fr_b, T, s_mm);
    // 5. output (reads ws only; overwrites all of d_out)
    out_kernel<<<dim3((MT * HD / 4) / 256), dim3(256), 0, stream>>>(s_txt, s_mm, T, out);
}

// Round 5
// 271.797 us; speedup vs baseline: 1.7342x; 1.7342x over previous
//
#include <hip/hip_runtime.h>
#include <hip/hip_bf16.h>
#include <math.h>

// Problem dims
constexpr int BD = 32;
constexpr int SD = 512;
constexpr int RD = 49;
constexpr int HD = 768;
constexpr int MT = BD * SD;    // 16384 text rows
constexpr int MI = BD * RD;    // 1568 img rows
constexpr int NP = 6;          // 3 n-blocks x 2 wave-columns partials per row
// 256x256 gemm geometry
constexpr int MBT3 = MT / 256; // 64 text m-blocks
constexpr int MBI3 = 7;        // img m-blocks (1792 padded rows; OOB reads land in wt_t, in-bounds)
constexpr int NB3 = 3;         // 768/256 n-blocks
constexpr int NWG3 = (MBT3 + MBI3) * NB3;  // 213 blocks
constexpr int NT3 = HD / 64;   // 12 K-steps (BK=64)

typedef __bf16 bf16;
typedef __bf16 bf16x4 __attribute__((ext_vector_type(4)));
typedef __bf16 bf16x8 __attribute__((ext_vector_type(8)));
typedef float f32x4 __attribute__((ext_vector_type(4)));

#define GLOAD_LDS16(g, l) __builtin_amdgcn_global_load_lds( \
    (__attribute__((address_space(1))) void*)(g),           \
    (__attribute__((address_space(3))) void*)(l), 16, 0, 0)
#define BAR() __builtin_amdgcn_s_barrier()
#define SCHED_FENCE() __builtin_amdgcn_sched_barrier(0)
#define WAITV(n) asm volatile("s_waitcnt vmcnt(" #n ")" ::: "memory")

__device__ __forceinline__ float fast_tanh(float x) {
    const float e = __expf(2.f * x);
    return 1.f - 2.f / (e + 1.f);
}

// ---------------------------------------------------------------------------
// prep_text: text fp32 -> text_bf (bf16) AND s_txt[row] = text[row,:].v_f
// ---------------------------------------------------------------------------
__global__ __launch_bounds__(256) void prep_text(
    const float* __restrict__ text, const float* __restrict__ v_f,
    bf16* __restrict__ text_bf, float* __restrict__ s_txt)
{
    const int row = blockIdx.x * 4 + (threadIdx.x >> 6);
    const int lane = threadIdx.x & 63;
    const float* tr = text + (size_t)row * HD;
    bf16* tb = text_bf + (size_t)row * HD;
    float acc = 0.f;
    #pragma unroll
    for (int c = 0; c < 3; ++c) {
        const int o = c * 256 + lane * 4;
        const f32x4 x = *(const f32x4*)(tr + o);
        const f32x4 v = *(const f32x4*)(v_f + o);
        bf16x4 b; b[0] = (bf16)x[0]; b[1] = (bf16)x[1]; b[2] = (bf16)x[2]; b[3] = (bf16)x[3];
        *(bf16x4*)(tb + o) = b;
        acc += x[0] * v[0] + x[1] * v[1] + x[2] * v[2] + x[3] * v[3];
    }
    for (int off = 32; off; off >>= 1) acc += __shfl_xor(acc, off);
    if (lane == 0) s_txt[row] = acc;
}

// ---------------------------------------------------------------------------
// prep_misc: fused vf_vm (385 blk) + conv_img (588 blk) + transpose_w (288 blk)
// ---------------------------------------------------------------------------
__global__ __launch_bounds__(256) void prep_misc(
    const float* __restrict__ ft_w, const float* __restrict__ fm_w,
    const float* __restrict__ fm_b, const float* __restrict__ fg_w,
    float* __restrict__ v_f, float* __restrict__ v_m, float* __restrict__ c_m,
    const float* __restrict__ img, bf16* __restrict__ img_bf,
    const float* __restrict__ t2_w, const float* __restrict__ i1_w,
    bf16* __restrict__ wt_t, bf16* __restrict__ wt_i)
{
    __shared__ float tile[64][65];
    const int bid = blockIdx.x;
    if (bid < 385) {
        const int idx = bid * 4 + (threadIdx.x >> 6);
        const int lane = threadIdx.x & 63;
        const float* row; const float* vecp; float* outp;
        if (idx < HD)            { row = ft_w + (size_t)idx * HD;        vecp = fg_w;      outp = v_f + idx; }
        else if (idx < 2 * HD)   { row = fm_w + (size_t)(idx - HD) * HD; vecp = fg_w + HD; outp = v_m + (idx - HD); }
        else if (idx == 2 * HD)  { row = fm_b;                           vecp = fg_w + HD; outp = c_m; }
        else return;
        float acc = 0.f;
        #pragma unroll
        for (int i = 0; i < HD / 64; ++i) acc += row[lane + 64 * i] * vecp[lane + 64 * i];
        for (int off = 32; off; off >>= 1) acc += __shfl_xor(acc, off);
        if (lane == 0) *outp = acc;
    } else if (bid < 385 + 588) {
        const int i = (bid - 385) * 256 + threadIdx.x;
        const int n8 = BD * RD * HD / 8;
        if (i >= n8) return;
        const size_t o = (size_t)i * 8;
        const f32x4 x0 = *(const f32x4*)(img + o);
        const f32x4 x1 = *(const f32x4*)(img + o + 4);
        bf16x8 b;
        b[0]=(bf16)x0[0]; b[1]=(bf16)x0[1]; b[2]=(bf16)x0[2]; b[3]=(bf16)x0[3];
        b[4]=(bf16)x1[0]; b[5]=(bf16)x1[1]; b[6]=(bf16)x1[2]; b[7]=(bf16)x1[3];
        *(bf16x8*)(img_bf + o) = b;
    } else {
        const int idx2 = bid - (385 + 588);
        const int z = idx2 / 144, rem = idx2 % 144;
        const int bx = rem % 12, by = rem / 12;
        const float* W = z ? i1_w : t2_w;
        bf16* Wt = z ? wt_i : wt_t;
        const int k0 = bx * 64, n0 = by * 64;
        const int t = threadIdx.x;
        const int rb = t >> 6, c = t & 63;
        #pragma unroll
        for (int i = 0; i < 16; ++i) {
            const int r = rb + i * 4;
            tile[r][c] = W[(size_t)(k0 + r) * HD + n0 + c];
        }
        __syncthreads();
        #pragma unroll
        for (int i = 0; i < 16; ++i) {
            const int r = rb + i * 4;
            Wt[(size_t)(n0 + r) * HD + k0 + c] = (bf16)tile[c][r];
        }
    }
}

// ---------------------------------------------------------------------------
// gemm3: merged score GEMMs, 256x256 tile, BK=64, 8 waves (512 thr),
// double-buffered LDS (128KB), depth-1 prefetch with counted vmcnt(8),
// conflict-free chunked LDS [khalf][rowchunk16][kq][row][8], XCD swizzle.
// Halves staged bytes vs 128^2 (167MB total); grid 213 = single generation.
// part[row][nb*2 + wn] = sum_{128-col slice} tanh((A@W)[row,n]) * vec[n]
// ---------------------------------------------------------------------------
__global__ __launch_bounds__(512, 2) void gemm3(
    const bf16* __restrict__ Atext, const bf16* __restrict__ WtT,
    const float* __restrict__ vecT, float* __restrict__ partT,
    const bf16* __restrict__ Aimg, const bf16* __restrict__ WtI,
    const float* __restrict__ vecI, float* __restrict__ partI)
{
    __shared__ __align__(16) bf16 As[2 * 16384];   // 2 bufs x 32KB
    __shared__ __align__(16) bf16 Bs[2 * 16384];

    // bijective XCD swizzle (m204)
    const int bid = blockIdx.x;
    const int q = NWG3 / 8, r = NWG3 % 8;
    const int xcd = bid % 8, sidx = bid / 8;
    const int o = (xcd < r ? xcd * (q + 1) : r * (q + 1) + (xcd - r) * q) + sidx;
    const int mb = o / NB3, nb = o % NB3;

    const bool isT = mb < MBT3;
    const bf16* A    = isT ? Atext : Aimg;
    const bf16* Wt   = isT ? WtT : WtI;
    const float* vec = isT ? vecT : vecI;
    float* part      = isT ? partT : partI;
    const int m0 = (isT ? mb : mb - MBT3) * 256;
    const int n0 = nb * 256;

    const int t = threadIdx.x;
    const int w = t >> 6, lane = t & 63;
    const int quad = lane >> 4, l16 = lane & 15;
    const int wm_idx = w & 3, wn_idx = w >> 2;     // 4 m-strips x 2 n-strips
    const int wm2 = wm_idx * 64, wn2 = wn_idx * 128;

    // staging: piece (h, rc) = 16 rows x 32 k, LDS order [kq][row16][8].
    // per-lane global src row l16, col quad*8; LDS dest wave-uniform (+lane*16B).
    const bf16* Ag = A  + (size_t)(m0 + l16) * HD + quad * 8;
    const bf16* Bg = Wt + (size_t)(n0 + l16) * HD + quad * 8;

    f32x4 acc[4][8] = {};

#define STAGE3(tt, bb) {                                                     \
    const int kk = (tt) * 64;                                                \
    _Pragma("unroll")                                                        \
    for (int h = 0; h < 2; ++h) {                                            \
        _Pragma("unroll")                                                    \
        for (int j = 0; j < 2; ++j) {                                        \
            const int rc = 2 * w + j;                                        \
            GLOAD_LDS16(Ag + (size_t)rc * 16 * HD + kk + h * 32,             \
                        As + (bb) * 16384 + (h * 16 + rc) * 512);            \
            GLOAD_LDS16(Bg + (size_t)rc * 16 * HD + kk + h * 32,             \
                        Bs + (bb) * 16384 + (h * 16 + rc) * 512);            \
        }                                                                    \
    }                                                                        \
}

#define COMPUTE3(bb) {                                                       \
    _Pragma("unroll")                                                        \
    for (int h = 0; h < 2; ++h) {                                            \
        bf16x8 af[4], bg[8];                                                 \
        _Pragma("unroll")                                                    \
        for (int fi = 0; fi < 4; ++fi)                                       \
            af[fi] = *(const bf16x8*)(As + (bb) * 16384 +                    \
                       (h * 16 + wm_idx * 4 + fi) * 512 + lane * 8);         \
        _Pragma("unroll")                                                    \
        for (int fj = 0; fj < 8; ++fj)                                       \
            bg[fj] = *(const bf16x8*)(Bs + (bb) * 16384 +                    \
                       (h * 16 + wn_idx * 8 + fj) * 512 + lane * 8);         \
        _Pragma("unroll")                                                    \
        for (int fi = 0; fi < 4; ++fi)                                       \
            _Pragma("unroll")                                                \
            for (int fj = 0; fj < 8; ++fj)                                   \
                acc[fi][fj] = __builtin_amdgcn_mfma_f32_16x16x32_bf16(       \
                    af[fi], bg[fj], acc[fi][fj], 0, 0, 0);                   \
    }                                                                        \
}

    STAGE3(0, 0);
    for (int tt = 0; tt < NT3 - 1; ++tt) {
        STAGE3(tt + 1, (tt + 1) & 1);
        WAITV(8);          // tile tt's 8 loads done; tile tt+1's 8 in flight
        BAR();
        SCHED_FENCE();
        COMPUTE3(tt & 1);
        SCHED_FENCE();
        BAR();             // all waves done reading buf tt&1 before restage
    }
    WAITV(0);
    BAR();
    SCHED_FENCE();
    COMPUTE3((NT3 - 1) & 1);

#undef STAGE3
#undef COMPUTE3

    // epilogue: C/D layout col=l16, row=quad*4+reg
    float vv[8];
    #pragma unroll
    for (int fj = 0; fj < 8; ++fj) vv[fj] = vec[n0 + wn2 + fj * 16 + l16];

    #pragma unroll
    for (int fi = 0; fi < 4; ++fi) {
        #pragma unroll
        for (int reg = 0; reg < 4; ++reg) {
            float p = 0.f;
            #pragma unroll
            for (int fj = 0; fj < 8; ++fj)
                p += fast_tanh(acc[fi][fj][reg]) * vv[fj];
            p += __shfl_xor(p, 1);
            p += __shfl_xor(p, 2);
            p += __shfl_xor(p, 4);
            p += __shfl_xor(p, 8);
            if (l16 == 0) {
                const int row = m0 + wm2 + fi * 16 + quad * 4 + reg;
                part[(size_t)row * NP + nb * 2 + wn_idx] = p;
            }
        }
    }
}

// ---------------------------------------------------------------------------
// wsum2: fused partial-reduce + softmax + weighted sum.
// blocks [0,96): text (b, hy): softmax of batch b from k_part, then
//   atxt[b, hy-slice] = sum_j P[j] * text_bf[b,j,h]
// blocks [96,192): img (b, hy): same from i_part over img fp32 (J=49)
// ---------------------------------------------------------------------------
__global__ __launch_bounds__(256) void wsum2(
    const float* __restrict__ k_part, const float* __restrict__ i_part,
    const bf16* __restrict__ text_bf, const float* __restrict__ img,
    float* __restrict__ atxt, float* __restrict__ aimg)
{
    __shared__ float S[SD];
    __shared__ float red[4];
    const int bid = blockIdx.x;
    const bool isText = bid < 96;
    const int idx = isText ? bid : bid - 96;
    const int b = idx & 31, hy = idx >> 5;
    const int t = threadIdx.x;

    if (isText) {
        for (int j = t; j < SD; j += 256) {
            const float* p = k_part + (size_t)(b * SD + j) * NP;
            float s = 0.f;
            #pragma unroll
            for (int u = 0; u < NP; ++u) s += p[u];
            S[j] = s;
        }
        __syncthreads();
        float m = fmaxf(S[t], S[t + 256]);
        for (int off = 32; off; off >>= 1) m = fmaxf(m, __shfl_xor(m, off));
        if ((t & 63) == 0) red[t >> 6] = m;
        __syncthreads();
        m = fmaxf(fmaxf(red[0], red[1]), fmaxf(red[2], red[3]));
        float lsum = 0.f;
        {
            const float e0 = __expf(S[t] - m), e1 = __expf(S[t + 256] - m);
            S[t] = e0; S[t + 256] = e1;
            lsum = e0 + e1;
        }
        for (int off = 32; off; off >>= 1) lsum += __shfl_xor(lsum, off);
        __syncthreads();
        if ((t & 63) == 0) red[t >> 6] = lsum;
        __syncthreads();
        const float inv = 1.f / (red[0] + red[1] + red[2] + red[3]);
        const int h = hy * 256 + t;
        const bf16* Xb = text_bf + (size_t)b * SD * HD + h;
        float acc = 0.f;
        #pragma unroll 8
        for (int j = 0; j < SD; ++j) acc += S[j] * (float)Xb[(size_t)j * HD];
        atxt[b * HD + h] = acc * inv;
    } else {
        if (t < 64) {
            float s0 = -1e30f;
            if (t < RD) {
                const float* p = i_part + (size_t)(b * RD + t) * NP;
                float s = 0.f;
                #pragma unroll
                for (int u = 0; u < NP; ++u) s += p[u];
                s0 = s;
            }
            float m = s0;
            for (int off = 32; off; off >>= 1) m = fmaxf(m, __shfl_xor(m, off));
            float e = (t < RD) ? __expf(s0 - m) : 0.f;
            float lsum = e;
            for (int off = 32; off; off >>= 1) lsum += __shfl_xor(lsum, off);
            if (t < RD) S[t] = e;
            if (t == 0) red[0] = 1.f / lsum;
        }
        __syncthreads();
        const float inv = red[0];
        const int h = hy * 256 + t;
        const float* Xb = img + (size_t)b * RD * HD + h;
        float acc = 0.f;
        #pragma unroll 7
        for (int j = 0; j < RD; ++j) acc += S[j] * Xb[(size_t)j * HD];
        aimg[b * HD + h] = acc * inv;
    }
}

// ---------------------------------------------------------------------------
// ni/nt GEMV (proven R0 form): grid (BD, HD/64, 2), 256 thr
// ---------------------------------------------------------------------------
__global__ __launch_bounds__(256) void ni_nt_kernel(
    const float* __restrict__ aimg, const float* __restrict__ atxt,
    const float* __restrict__ gi_w, const float* __restrict__ gi_b,
    const float* __restrict__ gt_w, const float* __restrict__ gt_b,
    float* __restrict__ ni, float* __restrict__ nt)
{
    const int b = blockIdx.x, n0 = blockIdx.y * 64, which = blockIdx.z;
    const float* X = which ? atxt : aimg;
    const float* W = which ? gt_w : gi_w;
    const float* bias = which ? gt_b : gi_b;
    float* Y = which ? nt : ni;

    __shared__ float Xs[HD];
    __shared__ float partial[4][64];
    const int t = threadIdx.x;
    for (int h = t; h < HD; h += 256) Xs[h] = X[b * HD + h];
    __syncthreads();
    const int n = n0 + (t & 63), kq = t >> 6;
    float acc = 0.f;
    const float* Wp = W + (size_t)(kq * 192) * HD + n;
    #pragma unroll 8
    for (int h = 0; h < 192; ++h) acc += Xs[kq * 192 + h] * Wp[(size_t)h * HD];
    partial[kq][t & 63] = acc;
    __syncthreads();
    if (t < 64) {
        const float s = partial[0][t] + partial[1][t] + partial[2][t] + partial[3][t];
        Y[b * HD + n0 + t] = tanhf(s + bias[n0 + t]);
    }
}

// ---------------------------------------------------------------------------
// gateT (proven R3 form): fused gate_mix + T_kernel. grid (BD, 12).
// ---------------------------------------------------------------------------
__global__ __launch_bounds__(256) void gateT(
    const float* __restrict__ ni, const float* __restrict__ nt,
    const float* __restrict__ gg_w, const float* __restrict__ gg_b,
    const float* __restrict__ v_m, const float* __restrict__ c_m,
    const float* __restrict__ fg_b,
    const float* __restrict__ fr_w, const float* __restrict__ fr_b,
    float* __restrict__ T, float* __restrict__ s_mm)
{
    const int b = blockIdx.x, n0 = blockIdx.y * 64, t = threadIdx.x;
    __shared__ float Ni[HD], Nt[HD], Mm[HD];
    __shared__ float partial[4][64];
    __shared__ float red[4];
    __shared__ float gsh;

    float acc = 0.f;
    for (int n = t; n < HD; n += 256) {
        const float vi = ni[b * HD + n], vt = nt[b * HD + n];
        Ni[n] = vi; Nt[n] = vt;
        acc += vi * gg_w[n] + vt * gg_w[HD + n];
    }
    for (int off = 32; off; off >>= 1) acc += __shfl_xor(acc, off);
    if ((t & 63) == 0) red[t >> 6] = acc;
    __syncthreads();
    if (t == 0) gsh = 1.f / (1.f + expf(-(red[0] + red[1] + red[2] + red[3] + gg_b[0])));
    __syncthreads();
    const float g = gsh;
    float a2 = 0.f;
    for (int n = t; n < HD; n += 256) {
        const float m = g * Ni[n] + (1.f - g) * Nt[n];
        Mm[n] = m;
        a2 += m * v_m[n];
    }
    __syncthreads();
    const int n = n0 + (t & 63), kq = t >> 6;
    float tacc = 0.f;
    const float* Wp = fr_w + (size_t)(kq * 192) * HD + n;
    #pragma unroll 8
    for (int h = 0; h < 192; ++h) tacc += Mm[kq * 192 + h] * Wp[(size_t)h * HD];
    partial[kq][t & 63] = tacc;
    if (blockIdx.y == 0) {
        for (int off = 32; off; off >>= 1) a2 += __shfl_xor(a2, off);
        __syncthreads();
        if ((t & 63) == 0) red[t >> 6] = a2;
        __syncthreads();
        if (t == 0) s_mm[b] = red[0] + red[1] + red[2] + red[3] + *c_m + fg_b[0];
    } else {
        __syncthreads();
    }
    __syncthreads();
    if (t < 64) {
        const float s = partial[0][t] + partial[1][t] + partial[2][t] + partial[3][t];
        T[b * HD + n0 + t] = tanhf(s + fr_b[n0 + t]);
    }
}

// out[b,s,h] = sigmoid(s_txt[b,s] + s_mm[b]) * T[b,h]  (reads ws only)
__global__ __launch_bounds__(256) void out_kernel(const float* __restrict__ s_txt,
                                                  const float* __restrict__ s_mm,
                                                  const float* __restrict__ T,
                                                  float* __restrict__ out) {
    const size_t idx = ((size_t)blockIdx.x * 256 + threadIdx.x) * 4;
    const int h = (int)(idx % HD);
    const int bs = (int)(idx / HD);
    const int b = bs >> 9;
    float f = s_txt[bs] + s_mm[b];
    f = 1.f / (1.f + expf(-f));
    const float* Tp = T + b * HD + h;
    f32x4 o;
    o[0] = f * Tp[0]; o[1] = f * Tp[1]; o[2] = f * Tp[2]; o[3] = f * Tp[3];
    *(f32x4*)(out + idx) = o;
}

// ---------------------------------------------------------------------------
extern "C" void kernel_launch(void* const* d_in, const int* in_sizes, int n_in,
                              void* d_out, int out_size, void* d_ws, size_t ws_size,
                              hipStream_t stream) {
    const float* text = (const float*)d_in[0];
    const float* img  = (const float*)d_in[1];
    const float* i1_w = (const float*)d_in[4];
    const float* a1_w = (const float*)d_in[5];
    const float* t2_w = (const float*)d_in[7];
    const float* a2_w = (const float*)d_in[10];
    const float* gt_w = (const float*)d_in[12];
    const float* gt_b = (const float*)d_in[13];
    const float* gi_w = (const float*)d_in[14];
    const float* gi_b = (const float*)d_in[15];
    const float* gg_w = (const float*)d_in[16];
    const float* gg_b = (const float*)d_in[17];
    const float* ft_w = (const float*)d_in[18];
    const float* fm_w = (const float*)d_in[19];
    const float* fm_b = (const float*)d_in[20];
    const float* fg_w = (const float*)d_in[21];
    const float* fg_b = (const float*)d_in[22];
    const float* fr_w = (const float*)d_in[23];
    const float* fr_b = (const float*)d_in[24];
    float* out = (float*)d_out;

    // ---- scratch inside d_out (all uses precede out_kernel) ----
    float* sc_ = out;
    float* i_part  = sc_;                 // 1792*6 = 10752 (cap 38400)
    float* k_part  = sc_ + 38400;         // 16384*6 = 98304
    float* aimg    = sc_ + 449600;        // 24576
    float* atxt    = sc_ + 474176;        // 24576
    float* v_f     = sc_ + 498752;        // 768
    float* v_m     = sc_ + 499520;        // 768
    float* c_m     = sc_ + 500288;        // 1 (+pad)
    float* ni      = sc_ + 598656;        // 24576
    float* nt      = sc_ + 623232;        // 24576
    bf16* text_bf  = (bf16*)(sc_ + 672384);    // 12.58M bf16
    bf16* img_bf   = (bf16*)(sc_ + 6963840);   // 1204224 bf16
    bf16* wt_t     = (bf16*)(sc_ + 7565952);   // 589824 bf16 (absorbs img OOB reads)
    bf16* wt_i     = (bf16*)(sc_ + 7860864);   // 589824 bf16 (ends 8155776 < 12.58M)

    // ---- ws holds only what out_kernel reads ----
    float* ws    = (float*)d_ws;
    float* s_txt = ws;                    // 16384
    float* s_mm  = ws + 16384;            // 32 (+pad)
    float* T     = ws + 16448;            // 24576

    // 0. fused prep: rank-1 collapses + img->bf16 + weight transposes
    prep_misc<<<dim3(385 + 588 + 288), dim3(256), 0, stream>>>(
        ft_w, fm_w, fm_b, fg_w, v_f, v_m, c_m, img, img_bf, t2_w, i1_w, wt_t, wt_i);
    // 0b. text fp32 -> bf16 + s_txt (needs v_f)
    prep_text<<<dim3(MT / 4), dim3(256), 0, stream>>>(text, v_f, text_bf, s_txt);
    // 1/2. merged score GEMMs (256^2 tile, prefetched double-buffer)
    gemm3<<<dim3(NWG3), dim3(512), 0, stream>>>(
        text_bf, wt_t, a2_w + HD, k_part, img_bf, wt_i, a1_w + HD, i_part);
    // 3. fused reduce + softmax + weighted sums -> atxt, aimg
    wsum2<<<dim3(192), dim3(256), 0, stream>>>(
        k_part, i_part, text_bf, img, atxt, aimg);
    // 4. GMF GEMVs (proven forms, large grids)
    ni_nt_kernel<<<dim3(BD, HD / 64, 2), dim3(256), 0, stream>>>(
        aimg, atxt, gi_w, gi_b, gt_w, gt_b, ni, nt);
    gateT<<<dim3(BD, HD / 64), dim3(256), 0, stream>>>(
        ni, nt, gg_w, gg_b, v_m, c_m, fg_b, fr_w, fr_b, T, s_mm);
    // 5. output (reads ws only; overwrites all of d_out)
    out_kernel<<<dim3((MT * HD / 4) / 256), dim3(256), 0, stream>>>(s_txt, s_mm, T, out);
}

// Round 6
// 252.593 us; speedup vs baseline: 1.8661x; 1.0760x over previous
//
#include <hip/hip_runtime.h>
#include <hip/hip_bf16.h>
#include <math.h>

// Problem dims
constexpr int BD = 32;
constexpr int SD = 512;
constexpr int RD = 49;
constexpr int HD = 768;
constexpr int MT = BD * SD;    // 16384 text rows
constexpr int MI = BD * RD;    // 1568 img rows
constexpr int NP = 6;          // 3 n-blocks x 2 wave-columns partials per row
// 256x256 gemm geometry
constexpr int MBT3 = MT / 256; // 64 text m-blocks
constexpr int MBI3 = 7;        // img m-blocks (1792 padded rows; OOB reads land in wt_t, in-bounds)
constexpr int NB3 = 3;         // 768/256 n-blocks
constexpr int NWG3 = (MBT3 + MBI3) * NB3;  // 213 blocks
constexpr int NT3 = HD / 64;   // 12 K-steps (BK=64)

typedef __bf16 bf16;
typedef __bf16 bf16x4 __attribute__((ext_vector_type(4)));
typedef __bf16 bf16x8 __attribute__((ext_vector_type(8)));
typedef float f32x4 __attribute__((ext_vector_type(4)));

#define GLOAD_LDS16(g, l) __builtin_amdgcn_global_load_lds( \
    (__attribute__((address_space(1))) void*)(g),           \
    (__attribute__((address_space(3))) void*)(l), 16, 0, 0)
#define BAR() __builtin_amdgcn_s_barrier()
#define SCHED_FENCE() __builtin_amdgcn_sched_barrier(0)
#define WAITV(n) asm volatile("s_waitcnt vmcnt(" #n ")" ::: "memory")

__device__ __forceinline__ float fast_tanh(float x) {
    const float e = __expf(2.f * x);
    return 1.f - 2.f / (e + 1.f);
}

// ---------------------------------------------------------------------------
// prep_text: text fp32 -> text_bf (bf16) AND s_txt[row] = text[row,:].v_f
// ---------------------------------------------------------------------------
__global__ __launch_bounds__(256) void prep_text(
    const float* __restrict__ text, const float* __restrict__ v_f,
    bf16* __restrict__ text_bf, float* __restrict__ s_txt)
{
    const int row = blockIdx.x * 4 + (threadIdx.x >> 6);
    const int lane = threadIdx.x & 63;
    const float* tr = text + (size_t)row * HD;
    bf16* tb = text_bf + (size_t)row * HD;
    float acc = 0.f;
    #pragma unroll
    for (int c = 0; c < 3; ++c) {
        const int o = c * 256 + lane * 4;
        const f32x4 x = *(const f32x4*)(tr + o);
        const f32x4 v = *(const f32x4*)(v_f + o);
        bf16x4 b; b[0] = (bf16)x[0]; b[1] = (bf16)x[1]; b[2] = (bf16)x[2]; b[3] = (bf16)x[3];
        *(bf16x4*)(tb + o) = b;
        acc += x[0] * v[0] + x[1] * v[1] + x[2] * v[2] + x[3] * v[3];
    }
    for (int off = 32; off; off >>= 1) acc += __shfl_xor(acc, off);
    if (lane == 0) s_txt[row] = acc;
}

// ---------------------------------------------------------------------------
// prep_misc: fused vf_vm (385 blk) + conv_img (588 blk) + transpose_w (288 blk)
// ---------------------------------------------------------------------------
__global__ __launch_bounds__(256) void prep_misc(
    const float* __restrict__ ft_w, const float* __restrict__ fm_w,
    const float* __restrict__ fm_b, const float* __restrict__ fg_w,
    float* __restrict__ v_f, float* __restrict__ v_m, float* __restrict__ c_m,
    const float* __restrict__ img, bf16* __restrict__ img_bf,
    const float* __restrict__ t2_w, const float* __restrict__ i1_w,
    bf16* __restrict__ wt_t, bf16* __restrict__ wt_i)
{
    __shared__ float tile[64][65];
    const int bid = blockIdx.x;
    if (bid < 385) {
        const int idx = bid * 4 + (threadIdx.x >> 6);
        const int lane = threadIdx.x & 63;
        const float* row; const float* vecp; float* outp;
        if (idx < HD)            { row = ft_w + (size_t)idx * HD;        vecp = fg_w;      outp = v_f + idx; }
        else if (idx < 2 * HD)   { row = fm_w + (size_t)(idx - HD) * HD; vecp = fg_w + HD; outp = v_m + (idx - HD); }
        else if (idx == 2 * HD)  { row = fm_b;                           vecp = fg_w + HD; outp = c_m; }
        else return;
        float acc = 0.f;
        #pragma unroll
        for (int i = 0; i < HD / 64; ++i) acc += row[lane + 64 * i] * vecp[lane + 64 * i];
        for (int off = 32; off; off >>= 1) acc += __shfl_xor(acc, off);
        if (lane == 0) *outp = acc;
    } else if (bid < 385 + 588) {
        const int i = (bid - 385) * 256 + threadIdx.x;
        const int n8 = BD * RD * HD / 8;
        if (i >= n8) return;
        const size_t o = (size_t)i * 8;
        const f32x4 x0 = *(const f32x4*)(img + o);
        const f32x4 x1 = *(const f32x4*)(img + o + 4);
        bf16x8 b;
        b[0]=(bf16)x0[0]; b[1]=(bf16)x0[1]; b[2]=(bf16)x0[2]; b[3]=(bf16)x0[3];
        b[4]=(bf16)x1[0]; b[5]=(bf16)x1[1]; b[6]=(bf16)x1[2]; b[7]=(bf16)x1[3];
        *(bf16x8*)(img_bf + o) = b;
    } else {
        const int idx2 = bid - (385 + 588);
        const int z = idx2 / 144, rem = idx2 % 144;
        const int bx = rem % 12, by = rem / 12;
        const float* W = z ? i1_w : t2_w;
        bf16* Wt = z ? wt_i : wt_t;
        const int k0 = bx * 64, n0 = by * 64;
        const int t = threadIdx.x;
        const int rb = t >> 6, c = t & 63;
        #pragma unroll
        for (int i = 0; i < 16; ++i) {
            const int r = rb + i * 4;
            tile[r][c] = W[(size_t)(k0 + r) * HD + n0 + c];
        }
        __syncthreads();
        #pragma unroll
        for (int i = 0; i < 16; ++i) {
            const int r = rb + i * 4;
            Wt[(size_t)(n0 + r) * HD + k0 + c] = (bf16)tile[c][r];
        }
    }
}

// ---------------------------------------------------------------------------
// gemm3: merged score GEMMs, 256x256 tile, BK=64, 8 waves (512 thr),
// double-buffered LDS (128KB), depth-1 prefetch with counted vmcnt(8),
// conflict-free chunked LDS, XCD swizzle. (FROZEN from R5: 49.6us measured)
// ---------------------------------------------------------------------------
__global__ __launch_bounds__(512, 2) void gemm3(
    const bf16* __restrict__ Atext, const bf16* __restrict__ WtT,
    const float* __restrict__ vecT, float* __restrict__ partT,
    const bf16* __restrict__ Aimg, const bf16* __restrict__ WtI,
    const float* __restrict__ vecI, float* __restrict__ partI)
{
    __shared__ __align__(16) bf16 As[2 * 16384];
    __shared__ __align__(16) bf16 Bs[2 * 16384];

    const int bid = blockIdx.x;
    const int q = NWG3 / 8, r = NWG3 % 8;
    const int xcd = bid % 8, sidx = bid / 8;
    const int o = (xcd < r ? xcd * (q + 1) : r * (q + 1) + (xcd - r) * q) + sidx;
    const int mb = o / NB3, nb = o % NB3;

    const bool isT = mb < MBT3;
    const bf16* A    = isT ? Atext : Aimg;
    const bf16* Wt   = isT ? WtT : WtI;
    const float* vec = isT ? vecT : vecI;
    float* part      = isT ? partT : partI;
    const int m0 = (isT ? mb : mb - MBT3) * 256;
    const int n0 = nb * 256;

    const int t = threadIdx.x;
    const int w = t >> 6, lane = t & 63;
    const int quad = lane >> 4, l16 = lane & 15;
    const int wm_idx = w & 3, wn_idx = w >> 2;
    const int wm2 = wm_idx * 64, wn2 = wn_idx * 128;

    const bf16* Ag = A  + (size_t)(m0 + l16) * HD + quad * 8;
    const bf16* Bg = Wt + (size_t)(n0 + l16) * HD + quad * 8;

    f32x4 acc[4][8] = {};

#define STAGE3(tt, bb) {                                                     \
    const int kk = (tt) * 64;                                                \
    _Pragma("unroll")                                                        \
    for (int h = 0; h < 2; ++h) {                                            \
        _Pragma("unroll")                                                    \
        for (int j = 0; j < 2; ++j) {                                        \
            const int rc = 2 * w + j;                                        \
            GLOAD_LDS16(Ag + (size_t)rc * 16 * HD + kk + h * 32,             \
                        As + (bb) * 16384 + (h * 16 + rc) * 512);            \
            GLOAD_LDS16(Bg + (size_t)rc * 16 * HD + kk + h * 32,             \
                        Bs + (bb) * 16384 + (h * 16 + rc) * 512);            \
        }                                                                    \
    }                                                                        \
}

#define COMPUTE3(bb) {                                                       \
    _Pragma("unroll")                                                        \
    for (int h = 0; h < 2; ++h) {                                            \
        bf16x8 af[4], bg[8];                                                 \
        _Pragma("unroll")                                                    \
        for (int fi = 0; fi < 4; ++fi)                                       \
            af[fi] = *(const bf16x8*)(As + (bb) * 16384 +                    \
                       (h * 16 + wm_idx * 4 + fi) * 512 + lane * 8);         \
        _Pragma("unroll")                                                    \
        for (int fj = 0; fj < 8; ++fj)                                       \
            bg[fj] = *(const bf16x8*)(Bs + (bb) * 16384 +                    \
                       (h * 16 + wn_idx * 8 + fj) * 512 + lane * 8);         \
        _Pragma("unroll")                                                    \
        for (int fi = 0; fi < 4; ++fi)                                       \
            _Pragma("unroll")                                                \
            for (int fj = 0; fj < 8; ++fj)                                   \
                acc[fi][fj] = __builtin_amdgcn_mfma_f32_16x16x32_bf16(       \
                    af[fi], bg[fj], acc[fi][fj], 0, 0, 0);                   \
    }                                                                        \
}

    STAGE3(0, 0);
    for (int tt = 0; tt < NT3 - 1; ++tt) {
        STAGE3(tt + 1, (tt + 1) & 1);
        WAITV(8);
        BAR();
        SCHED_FENCE();
        COMPUTE3(tt & 1);
        SCHED_FENCE();
        BAR();
    }
    WAITV(0);
    BAR();
    SCHED_FENCE();
    COMPUTE3((NT3 - 1) & 1);

#undef STAGE3
#undef COMPUTE3

    float vv[8];
    #pragma unroll
    for (int fj = 0; fj < 8; ++fj) vv[fj] = vec[n0 + wn2 + fj * 16 + l16];

    #pragma unroll
    for (int fi = 0; fi < 4; ++fi) {
        #pragma unroll
        for (int reg = 0; reg < 4; ++reg) {
            float p = 0.f;
            #pragma unroll
            for (int fj = 0; fj < 8; ++fj)
                p += fast_tanh(acc[fi][fj][reg]) * vv[fj];
            p += __shfl_xor(p, 1);
            p += __shfl_xor(p, 2);
            p += __shfl_xor(p, 4);
            p += __shfl_xor(p, 8);
            if (l16 == 0) {
                const int row = m0 + wm2 + fi * 16 + quad * 4 + reg;
                part[(size_t)row * NP + nb * 2 + wn_idx] = p;
            }
        }
    }
}

// ---------------------------------------------------------------------------
// wsum3: fused partial-reduce + softmax + weighted sum, VECTORIZED.
// blocks [0,128): text (b = bid>>2, jq = bid&3): recompute softmax of batch b
//   from k_part, then at_part[(b*4+jq)*HD + h] = sum_{j in jq-quarter} P[j]*X
//   via bf16x8 loads, thread (o = t%96 octet, jh = t/96 of 2) 64-deep chains.
// blocks [128,224): img (b, hy): softmax from i_part then aimg slice (J=49).
// ---------------------------------------------------------------------------
__global__ __launch_bounds__(256) void wsum3(
    const float* __restrict__ k_part, const float* __restrict__ i_part,
    const bf16* __restrict__ text_bf, const float* __restrict__ img,
    float* __restrict__ at_part, float* __restrict__ aimg)
{
    __shared__ float S[SD];
    __shared__ float red[4];
    __shared__ float P2[2][96][8];
    const int bid = blockIdx.x;
    const int t = threadIdx.x;

    if (bid < 128) {
        const int b = bid >> 2, jq = bid & 3;
        // full softmax recompute from k_part (12KB)
        for (int j = t; j < SD; j += 256) {
            const float* p = k_part + (size_t)(b * SD + j) * NP;
            S[j] = p[0] + p[1] + p[2] + p[3] + p[4] + p[5];
        }
        __syncthreads();
        float m = fmaxf(S[t], S[t + 256]);
        for (int off = 32; off; off >>= 1) m = fmaxf(m, __shfl_xor(m, off));
        if ((t & 63) == 0) red[t >> 6] = m;
        __syncthreads();
        m = fmaxf(fmaxf(red[0], red[1]), fmaxf(red[2], red[3]));
        const float e0 = __expf(S[t] - m), e1 = __expf(S[t + 256] - m);
        S[t] = e0; S[t + 256] = e1;
        float lsum = e0 + e1;
        for (int off = 32; off; off >>= 1) lsum += __shfl_xor(lsum, off);
        __syncthreads();
        if ((t & 63) == 0) red[t >> 6] = lsum;
        __syncthreads();
        const float inv = 1.f / (red[0] + red[1] + red[2] + red[3]);
        // weighted sum: thread (o, jh) accumulates 8 h over 64 j (bf16x8 loads)
        const int o = t % 96, jh = t / 96;
        if (jh < 2) {
            float a[8] = {};
            const bf16* Xb = text_bf + ((size_t)b * SD + jq * 128 + jh * 64) * HD + o * 8;
            const float* Sp = S + jq * 128 + jh * 64;
            #pragma unroll 8
            for (int jj = 0; jj < 64; ++jj) {
                const bf16x8 v = *(const bf16x8*)(Xb + (size_t)jj * HD);
                const float s = Sp[jj];
                #pragma unroll
                for (int e = 0; e < 8; ++e) a[e] += s * (float)v[e];
            }
            #pragma unroll
            for (int e = 0; e < 8; ++e) P2[jh][o][e] = a[e];
        }
        __syncthreads();
        if (t < 96) {
            float* dst = at_part + ((size_t)(b * 4 + jq)) * HD + t * 8;
            f32x4 o0, o1;
            #pragma unroll
            for (int e = 0; e < 4; ++e) o0[e] = (P2[0][t][e] + P2[1][t][e]) * inv;
            #pragma unroll
            for (int e = 0; e < 4; ++e) o1[e] = (P2[0][t][e + 4] + P2[1][t][e + 4]) * inv;
            *(f32x4*)dst = o0;
            *(f32x4*)(dst + 4) = o1;
        }
    } else {
        const int idx = bid - 128;
        const int b = idx & 31, hy = idx >> 5;
        if (t < 64) {
            float s0 = -1e30f;
            if (t < RD) {
                const float* p = i_part + (size_t)(b * RD + t) * NP;
                s0 = p[0] + p[1] + p[2] + p[3] + p[4] + p[5];
            }
            float m = s0;
            for (int off = 32; off; off >>= 1) m = fmaxf(m, __shfl_xor(m, off));
            float e = (t < RD) ? __expf(s0 - m) : 0.f;
            float lsum = e;
            for (int off = 32; off; off >>= 1) lsum += __shfl_xor(lsum, off);
            if (t < RD) S[t] = e;
            if (t == 0) red[0] = 1.f / lsum;
        }
        __syncthreads();
        const float inv = red[0];
        const int h = hy * 256 + t;
        const float* Xb = img + (size_t)b * RD * HD + h;
        float acc = 0.f;
        #pragma unroll 7
        for (int j = 0; j < RD; ++j) acc += S[j] * Xb[(size_t)j * HD];
        aimg[b * HD + h] = acc * inv;
    }
}

// ---------------------------------------------------------------------------
// ni_nt3: GEMV with f32x4 weight loads, 8-way K split. grid (32, 6, 2).
// which==1 folds the at_part 4-way reduce (atxt never materialized).
// ---------------------------------------------------------------------------
__global__ __launch_bounds__(256) void ni_nt3(
    const float* __restrict__ aimg, const float* __restrict__ at_part,
    const float* __restrict__ gi_w, const float* __restrict__ gi_b,
    const float* __restrict__ gt_w, const float* __restrict__ gt_b,
    float* __restrict__ ni, float* __restrict__ nt)
{
    const int b = blockIdx.x, n0 = blockIdx.y * 128, which = blockIdx.z;
    const float* W = which ? gt_w : gi_w;
    const float* bias = which ? gt_b : gi_b;
    float* Y = which ? nt : ni;

    __shared__ float Xs[HD];
    __shared__ float part[8][32][4];
    const int t = threadIdx.x;
    if (which) {
        for (int h = t; h < HD; h += 256)
            Xs[h] = at_part[((size_t)(b * 4 + 0)) * HD + h] + at_part[((size_t)(b * 4 + 1)) * HD + h]
                  + at_part[((size_t)(b * 4 + 2)) * HD + h] + at_part[((size_t)(b * 4 + 3)) * HD + h];
    } else {
        for (int h = t; h < HD; h += 256) Xs[h] = aimg[b * HD + h];
    }
    __syncthreads();
    const int lane32 = t & 31, kq = t >> 5;
    const int n = n0 + lane32 * 4;
    f32x4 acc = {0.f, 0.f, 0.f, 0.f};
    const float* Wp = W + (size_t)(kq * 96) * HD + n;
    #pragma unroll 4
    for (int k = 0; k < 96; ++k) {
        const f32x4 wv = *(const f32x4*)(Wp + (size_t)k * HD);
        const float x = Xs[kq * 96 + k];
        acc[0] += x * wv[0]; acc[1] += x * wv[1];
        acc[2] += x * wv[2]; acc[3] += x * wv[3];
    }
    *(f32x4*)&part[kq][lane32][0] = acc;
    __syncthreads();
    if (t < 128) {
        float s = 0.f;
        #pragma unroll
        for (int q2 = 0; q2 < 8; ++q2) s += part[q2][t >> 2][t & 3];
        Y[b * HD + n0 + t] = fast_tanh(s + bias[n0 + t]);
    }
}

// ---------------------------------------------------------------------------
// gateT3: fused gate_mix + T GEMV, f32x4 weight loads. grid (32, 6).
// ---------------------------------------------------------------------------
__global__ __launch_bounds__(256) void gateT3(
    const float* __restrict__ ni, const float* __restrict__ nt,
    const float* __restrict__ gg_w, const float* __restrict__ gg_b,
    const float* __restrict__ v_m, const float* __restrict__ c_m,
    const float* __restrict__ fg_b,
    const float* __restrict__ fr_w, const float* __restrict__ fr_b,
    float* __restrict__ T, float* __restrict__ s_mm)
{
    const int b = blockIdx.x, n0 = blockIdx.y * 128, t = threadIdx.x;
    __shared__ float Mm[HD];
    __shared__ float part[8][32][4];
    __shared__ float red[4];
    __shared__ float gsh;

    float accg = 0.f;
    for (int n = t; n < HD; n += 256)
        accg += ni[b * HD + n] * gg_w[n] + nt[b * HD + n] * gg_w[HD + n];
    for (int off = 32; off; off >>= 1) accg += __shfl_xor(accg, off);
    if ((t & 63) == 0) red[t >> 6] = accg;
    __syncthreads();
    if (t == 0) gsh = 1.f / (1.f + expf(-(red[0] + red[1] + red[2] + red[3] + gg_b[0])));
    __syncthreads();
    const float g = gsh;
    float a2 = 0.f;
    for (int n = t; n < HD; n += 256) {
        const float m = g * ni[b * HD + n] + (1.f - g) * nt[b * HD + n];
        Mm[n] = m;
        a2 += m * v_m[n];
    }
    __syncthreads();
    // T GEMV slice
    const int lane32 = t & 31, kq = t >> 5;
    const int n = n0 + lane32 * 4;
    f32x4 acc = {0.f, 0.f, 0.f, 0.f};
    const float* Wp = fr_w + (size_t)(kq * 96) * HD + n;
    #pragma unroll 4
    for (int k = 0; k < 96; ++k) {
        const f32x4 wv = *(const f32x4*)(Wp + (size_t)k * HD);
        const float x = Mm[kq * 96 + k];
        acc[0] += x * wv[0]; acc[1] += x * wv[1];
        acc[2] += x * wv[2]; acc[3] += x * wv[3];
    }
    *(f32x4*)&part[kq][lane32][0] = acc;
    if (blockIdx.y == 0) {
        for (int off = 32; off; off >>= 1) a2 += __shfl_xor(a2, off);
        if ((t & 63) == 0) red[t >> 6] = a2;
    }
    __syncthreads();
    if (blockIdx.y == 0 && t == 0)
        s_mm[b] = red[0] + red[1] + red[2] + red[3] + *c_m + fg_b[0];
    if (t < 128) {
        float s = 0.f;
        #pragma unroll
        for (int q2 = 0; q2 < 8; ++q2) s += part[q2][t >> 2][t & 3];
        T[b * HD + n0 + t] = fast_tanh(s + fr_b[n0 + t]);
    }
}

// out[b,s,h] = sigmoid(s_txt[b,s] + s_mm[b]) * T[b,h]  (reads ws only)
__global__ __launch_bounds__(256) void out_kernel(const float* __restrict__ s_txt,
                                                  const float* __restrict__ s_mm,
                                                  const float* __restrict__ T,
                                                  float* __restrict__ out) {
    const size_t idx = ((size_t)blockIdx.x * 256 + threadIdx.x) * 4;
    const int h = (int)(idx % HD);
    const int bs = (int)(idx / HD);
    const int b = bs >> 9;
    float f = s_txt[bs] + s_mm[b];
    f = 1.f / (1.f + expf(-f));
    const float* Tp = T + b * HD + h;
    f32x4 o;
    o[0] = f * Tp[0]; o[1] = f * Tp[1]; o[2] = f * Tp[2]; o[3] = f * Tp[3];
    *(f32x4*)(out + idx) = o;
}

// ---------------------------------------------------------------------------
extern "C" void kernel_launch(void* const* d_in, const int* in_sizes, int n_in,
                              void* d_out, int out_size, void* d_ws, size_t ws_size,
                              hipStream_t stream) {
    const float* text = (const float*)d_in[0];
    const float* img  = (const float*)d_in[1];
    const float* i1_w = (const float*)d_in[4];
    const float* a1_w = (const float*)d_in[5];
    const float* t2_w = (const float*)d_in[7];
    const float* a2_w = (const float*)d_in[10];
    const float* gt_w = (const float*)d_in[12];
    const float* gt_b = (const float*)d_in[13];
    const float* gi_w = (const float*)d_in[14];
    const float* gi_b = (const float*)d_in[15];
    const float* gg_w = (const float*)d_in[16];
    const float* gg_b = (const float*)d_in[17];
    const float* ft_w = (const float*)d_in[18];
    const float* fm_w = (const float*)d_in[19];
    const float* fm_b = (const float*)d_in[20];
    const float* fg_w = (const float*)d_in[21];
    const float* fg_b = (const float*)d_in[22];
    const float* fr_w = (const float*)d_in[23];
    const float* fr_b = (const float*)d_in[24];
    float* out = (float*)d_out;

    // ---- scratch inside d_out (all uses precede out_kernel) ----
    float* sc_ = out;
    float* i_part  = sc_;                 // 1792*6 = 10752 (cap 38400)
    float* k_part  = sc_ + 38400;         // 16384*6 = 98304
    float* aimg    = sc_ + 449600;        // 24576
    float* v_f     = sc_ + 498752;        // 768
    float* v_m     = sc_ + 499520;        // 768
    float* c_m     = sc_ + 500288;        // 1 (+pad)
    float* at_part = sc_ + 500352;        // 98304 (ends 598656)
    float* ni      = sc_ + 598656;        // 24576
    float* nt      = sc_ + 623232;        // 24576
    bf16* text_bf  = (bf16*)(sc_ + 672384);    // 12.58M bf16
    bf16* img_bf   = (bf16*)(sc_ + 6963840);   // 1204224 bf16
    bf16* wt_t     = (bf16*)(sc_ + 7565952);   // 589824 bf16 (absorbs img OOB reads)
    bf16* wt_i     = (bf16*)(sc_ + 7860864);   // 589824 bf16 (ends 8155776 < 12.58M)

    // ---- ws holds only what out_kernel reads ----
    float* ws    = (float*)d_ws;
    float* s_txt = ws;                    // 16384
    float* s_mm  = ws + 16384;            // 32 (+pad)
    float* T     = ws + 16448;            // 24576

    // 0. fused prep: rank-1 collapses + img->bf16 + weight transposes
    prep_misc<<<dim3(385 + 588 + 288), dim3(256), 0, stream>>>(
        ft_w, fm_w, fm_b, fg_w, v_f, v_m, c_m, img, img_bf, t2_w, i1_w, wt_t, wt_i);
    // 0b. text fp32 -> bf16 + s_txt (needs v_f)
    prep_text<<<dim3(MT / 4), dim3(256), 0, stream>>>(text, v_f, text_bf, s_txt);
    // 1/2. merged score GEMMs (256^2 tile, prefetched double-buffer)
    gemm3<<<dim3(NWG3), dim3(512), 0, stream>>>(
        text_bf, wt_t, a2_w + HD, k_part, img_bf, wt_i, a1_w + HD, i_part);
    // 3. fused reduce + softmax + weighted sums (vectorized) -> at_part, aimg
    wsum3<<<dim3(224), dim3(256), 0, stream>>>(
        k_part, i_part, text_bf, img, at_part, aimg);
    // 4. GMF GEMVs (f32x4 weight loads; ni_nt folds at_part reduce)
    ni_nt3<<<dim3(BD, 6, 2), dim3(256), 0, stream>>>(
        aimg, at_part, gi_w, gi_b, gt_w, gt_b, ni, nt);
    gateT3<<<dim3(BD, 6), dim3(256), 0, stream>>>(
        ni, nt, gg_w, gg_b, v_m, c_m, fg_b, fr_w, fr_b, T, s_mm);
    // 5. output (reads ws only; overwrites all of d_out)
    out_kernel<<<dim3((MT * HD / 4) / 256), dim3(256), 0, stream>>>(s_txt, s_mm, T, out);
}